// Round 1
// baseline (109112.524 us; speedup 1.0000x reference)
//
#include <hip/hip_runtime.h>

#define T_STEPS 2048
#define BATCH 8
#define HID 1024

// ws layout (floats unless noted):
//   [0, 50331648)                 x_proj  [B*T][3H], m = b*T + t
//   [50331648, 50331648+16384)    h double buffer: 2 x [B][H]
//   byte offset 201392128:        flags, T_STEPS * 256 u32 (poisoned 0xAA != 1)
#define XPROJ_F 50331648ull
#define HBUF_F  16384ull
#define FLAGS_BYTE_OFF 201392128ull

__device__ __forceinline__ float sigmoidf_(float x) {
    return 1.0f / (1.0f + __expf(-x));
}

// ---------------- Phase 1: x_proj = x @ W_ih^T + b_ih ----------------
// C[m][r] = sum_k x[m][k] * Wih[r][k] + bih[r];  M=16384, N=3072, K=1024.
// 128x128 tile, BK=16, 256 threads, each thread 8x8 micro-tile.
__global__ __launch_bounds__(256) void gemm_xproj(
        const float* __restrict__ x, const float* __restrict__ Wih,
        const float* __restrict__ bih, float* __restrict__ xproj) {
    __shared__ float a_lds[16][128];  // [k][m]
    __shared__ float b_lds[16][128];  // [k][n]
    const int tid = threadIdx.x;
    const int m0 = blockIdx.x * 128;
    const int n0 = blockIdx.y * 128;
    const int tx = tid & 15, ty = tid >> 4;

    float acc[8][8];
#pragma unroll
    for (int i = 0; i < 8; i++)
#pragma unroll
        for (int jj = 0; jj < 8; jj++) acc[i][jj] = 0.f;

    for (int k0 = 0; k0 < 1024; k0 += 16) {
#pragma unroll
        for (int l = 0; l < 2; l++) {
            const int c = tid + l * 256;   // 512 float4s per tile
            const int row = c >> 2;
            const int f4 = c & 3;
            float4 av = *reinterpret_cast<const float4*>(
                x + (size_t)(m0 + row) * 1024 + k0 + f4 * 4);
            float4 bv = *reinterpret_cast<const float4*>(
                Wih + (size_t)(n0 + row) * 1024 + k0 + f4 * 4);
            a_lds[f4 * 4 + 0][row] = av.x; a_lds[f4 * 4 + 1][row] = av.y;
            a_lds[f4 * 4 + 2][row] = av.z; a_lds[f4 * 4 + 3][row] = av.w;
            b_lds[f4 * 4 + 0][row] = bv.x; b_lds[f4 * 4 + 1][row] = bv.y;
            b_lds[f4 * 4 + 2][row] = bv.z; b_lds[f4 * 4 + 3][row] = bv.w;
        }
        __syncthreads();
#pragma unroll
        for (int kk = 0; kk < 16; kk++) {
            float a[8], b[8];
            *reinterpret_cast<float4*>(&a[0]) =
                *reinterpret_cast<float4*>(&a_lds[kk][ty * 8]);
            *reinterpret_cast<float4*>(&a[4]) =
                *reinterpret_cast<float4*>(&a_lds[kk][ty * 8 + 4]);
            *reinterpret_cast<float4*>(&b[0]) =
                *reinterpret_cast<float4*>(&b_lds[kk][tx * 8]);
            *reinterpret_cast<float4*>(&b[4]) =
                *reinterpret_cast<float4*>(&b_lds[kk][tx * 8 + 4]);
#pragma unroll
            for (int i = 0; i < 8; i++)
#pragma unroll
                for (int jj = 0; jj < 8; jj++)
                    acc[i][jj] = fmaf(a[i], b[jj], acc[i][jj]);
        }
        __syncthreads();
    }

    float bias[8];
    *reinterpret_cast<float4*>(&bias[0]) =
        *reinterpret_cast<const float4*>(bih + n0 + tx * 8);
    *reinterpret_cast<float4*>(&bias[4]) =
        *reinterpret_cast<const float4*>(bih + n0 + tx * 8 + 4);
#pragma unroll
    for (int i = 0; i < 8; i++) {
        float4 v0, v1;
        v0.x = acc[i][0] + bias[0]; v0.y = acc[i][1] + bias[1];
        v0.z = acc[i][2] + bias[2]; v0.w = acc[i][3] + bias[3];
        v1.x = acc[i][4] + bias[4]; v1.y = acc[i][5] + bias[5];
        v1.z = acc[i][6] + bias[6]; v1.w = acc[i][7] + bias[7];
        const size_t base = (size_t)(m0 + ty * 8 + i) * 3072 + n0 + tx * 8;
        *reinterpret_cast<float4*>(xproj + base) = v0;
        *reinterpret_cast<float4*>(xproj + base + 4) = v1;
    }
}

// ---------------- Phase 2: sequential GRU scan ----------------
// 256 blocks x 256 threads, all co-resident (1 block/CU on a 256-CU chip).
// Block bid owns j in [bid*4, bid*4+4); wave w handles j = bid*4 + w (all 3
// gates, all 8 batches). W_hh rows live in VGPRs (48 floats/lane),
// loop-invariant. Per step: poll flags of all 256 blocks (1 flag/thread),
// load h (device-coherent after fence), 384 reg-reg FMAs/lane, wave
// butterfly-reduce, gate math on lanes 0..7, store h_new + out, release flag.
__global__ __launch_bounds__(256, 1) void gru_scan(
        const float* __restrict__ Whh, const float* __restrict__ bhh,
        const float* __restrict__ xproj, float* __restrict__ out,
        float* __restrict__ hbuf, unsigned int* __restrict__ flags) {
    const int tid = threadIdx.x;
    const int bid = blockIdx.x;
    const int wave = tid >> 6;
    const int lane = tid & 63;
    const int j = bid * 4 + wave;        // [0, 1024)

    // loop-invariant W_hh fragment: rows g*1024+j, k in [lane*16, lane*16+16)
    float4 wf[3][4];
#pragma unroll
    for (int g = 0; g < 3; g++)
#pragma unroll
        for (int i = 0; i < 4; i++)
            wf[g][i] = *reinterpret_cast<const float4*>(
                Whh + (size_t)(g * 1024 + j) * 1024 + lane * 16 + i * 4);

    const float bh0 = bhh[j], bh1 = bhh[1024 + j], bh2 = bhh[2048 + j];

    // ---- t = 0: h_prev = 0 -> g_h = b_hh ----
    if (lane < 8) {
        const size_t xb = ((size_t)lane * T_STEPS + 0) * 3072 + j;
        const float gxr = xproj[xb];
        const float gxz = xproj[xb + 1024];
        const float gxn = xproj[xb + 2048];
        const float r = sigmoidf_(gxr + bh0);
        const float z = sigmoidf_(gxz + bh1);
        const float n = tanhf(gxn + r * bh2);
        const float hnew = (1.f - z) * n;
        hbuf[lane * HID + j] = hnew;
        out[((size_t)lane * T_STEPS) * HID + j] = hnew;
    }
    __threadfence();
    __syncthreads();
    if (tid == 0)
        __hip_atomic_store(&flags[bid], 1u, __ATOMIC_RELEASE,
                           __HIP_MEMORY_SCOPE_AGENT);

    for (int t = 1; t < T_STEPS; t++) {
        // prefetch gx for this step (independent of h / the barrier)
        float gxr = 0.f, gxz = 0.f, gxn = 0.f;
        if (lane < 8) {
            const size_t xb = ((size_t)lane * T_STEPS + t) * 3072 + j;
            gxr = xproj[xb];
            gxz = xproj[xb + 1024];
            gxn = xproj[xb + 2048];
        }

        // wait until every block finished step t-1 (one flag per thread)
        const unsigned int* fl = &flags[(size_t)(t - 1) * 256 + tid];
        while (__hip_atomic_load(fl, __ATOMIC_RELAXED,
                                 __HIP_MEMORY_SCOPE_AGENT) != 1u)
            __builtin_amdgcn_s_sleep(1);
        __syncthreads();
        __threadfence();  // acquire side: refetch h from coherence point

        const float* hsrc = hbuf + ((t - 1) & 1) * (BATCH * HID);
        float4 hr[8][4];
#pragma unroll
        for (int b = 0; b < 8; b++)
#pragma unroll
            for (int i = 0; i < 4; i++)
                hr[b][i] = *reinterpret_cast<const float4*>(
                    hsrc + b * HID + lane * 16 + i * 4);
        const float hprev = (lane < 8) ? hsrc[lane * HID + j] : 0.f;

        float acc[3][8];
#pragma unroll
        for (int g = 0; g < 3; g++)
#pragma unroll
            for (int b = 0; b < 8; b++) acc[g][b] = 0.f;
#pragma unroll
        for (int g = 0; g < 3; g++)
#pragma unroll
            for (int b = 0; b < 8; b++)
#pragma unroll
                for (int i = 0; i < 4; i++) {
                    acc[g][b] = fmaf(wf[g][i].x, hr[b][i].x, acc[g][b]);
                    acc[g][b] = fmaf(wf[g][i].y, hr[b][i].y, acc[g][b]);
                    acc[g][b] = fmaf(wf[g][i].z, hr[b][i].z, acc[g][b]);
                    acc[g][b] = fmaf(wf[g][i].w, hr[b][i].w, acc[g][b]);
                }

        // full-wave butterfly all-reduce over the 64-way K split
#pragma unroll
        for (int m = 32; m >= 1; m >>= 1)
#pragma unroll
            for (int g = 0; g < 3; g++)
#pragma unroll
                for (int b = 0; b < 8; b++)
                    acc[g][b] += __shfl_xor(acc[g][b], m);

        if (lane < 8) {
            float a0 = 0.f, a1 = 0.f, a2 = 0.f;
#pragma unroll
            for (int b = 0; b < 8; b++)
                if (lane == b) { a0 = acc[0][b]; a1 = acc[1][b]; a2 = acc[2][b]; }
            const float r = sigmoidf_(gxr + a0 + bh0);
            const float z = sigmoidf_(gxz + a1 + bh1);
            const float n = tanhf(gxn + r * (a2 + bh2));
            const float hnew = (1.f - z) * n + z * hprev;
            float* hdst = hbuf + (t & 1) * (BATCH * HID);
            hdst[lane * HID + j] = hnew;
            out[((size_t)lane * T_STEPS + t) * HID + j] = hnew;
        }
        __threadfence();
        __syncthreads();
        if (tid == 0)
            __hip_atomic_store(&flags[(size_t)t * 256 + bid], 1u,
                               __ATOMIC_RELEASE, __HIP_MEMORY_SCOPE_AGENT);
    }
}

extern "C" void kernel_launch(void* const* d_in, const int* in_sizes, int n_in,
                              void* d_out, int out_size, void* d_ws,
                              size_t ws_size, hipStream_t stream) {
    const float* x    = (const float*)d_in[0];
    const float* Wih  = (const float*)d_in[1];
    const float* bih  = (const float*)d_in[2];
    const float* Whh  = (const float*)d_in[3];
    const float* bhh  = (const float*)d_in[4];
    float* outp = (float*)d_out;

    float* xproj = (float*)d_ws;
    float* hbuf  = xproj + XPROJ_F;
    unsigned int* flags =
        (unsigned int*)((char*)d_ws + FLAGS_BYTE_OFF);

    dim3 g1(128, 24);   // M/128, N/128
    gemm_xproj<<<g1, 256, 0, stream>>>(x, Wih, bih, xproj);
    gru_scan<<<256, 256, 0, stream>>>(Whh, bhh, xproj, outp, hbuf, flags);
}

// Round 3
// 18688.506 us; speedup vs baseline: 5.8385x; 5.8385x over previous
//
#include <hip/hip_runtime.h>

#define T_STEPS 2048
#define BATCH 8
#define HID 1024

// ws layout (floats unless noted):
//   [0, 50331648)            x_proj repacked [t][gate][j][b]  (t*3072+g*1024+j)*8+b
//   [50331648, +16384)       h double buffer: 2 x [B][H]
//   byte off 201392128:      flags, T_STEPS * 256 u32 (poisoned 0xAA != 1)
#define XPROJ_F 50331648ull
#define FLAGS_BYTE_OFF 201392128ull

__device__ __forceinline__ float sigmoidf_(float x) {
    return 1.0f / (1.0f + __expf(-x));
}

// All cross-block-coherent traffic goes through relaxed AGENT-scope atomics
// (lower to global_load/store ... sc1: read/write the Infinity Cache, the
// inter-XCD coherence point; no L2 writeback/invalidate is ever emitted).
__device__ __forceinline__ float ld_f32_agent(const float* p) {
    return __hip_atomic_load(p, __ATOMIC_RELAXED, __HIP_MEMORY_SCOPE_AGENT);
}
__device__ __forceinline__ unsigned long long ld_u64_agent(const void* p) {
    return __hip_atomic_load((const unsigned long long*)p, __ATOMIC_RELAXED,
                             __HIP_MEMORY_SCOPE_AGENT);
}
__device__ __forceinline__ void st_f32_agent(float* p, float v) {
    __hip_atomic_store(p, v, __ATOMIC_RELAXED, __HIP_MEMORY_SCOPE_AGENT);
}
__device__ __forceinline__ void st_u32_agent(unsigned* p, unsigned v) {
    __hip_atomic_store(p, v, __ATOMIC_RELAXED, __HIP_MEMORY_SCOPE_AGENT);
}
__device__ __forceinline__ unsigned ld_u32_agent(const unsigned* p) {
    return __hip_atomic_load(p, __ATOMIC_RELAXED, __HIP_MEMORY_SCOPE_AGENT);
}
__device__ __forceinline__ void drain_vmem() {   // order sc1 stores before flag
    asm volatile("s_waitcnt vmcnt(0)" ::: "memory");
}

// ---------------- Phase 1: x_proj = x @ W_ih^T + b_ih ----------------
// 128x128 tile, BK=16, 256 threads, 8x8 micro-tile. Epilogue scatters into
// the [t][gate][j][b] layout the scan wants.
__global__ __launch_bounds__(256) void gemm_xproj(
        const float* __restrict__ x, const float* __restrict__ Wih,
        const float* __restrict__ bih, float* __restrict__ xproj) {
    __shared__ float a_lds[16][128];  // [k][m]
    __shared__ float b_lds[16][128];  // [k][n]
    const int tid = threadIdx.x;
    const int m0 = blockIdx.x * 128;
    const int n0 = blockIdx.y * 128;
    const int tx = tid & 15, ty = tid >> 4;

    float acc[8][8];
#pragma unroll
    for (int i = 0; i < 8; i++)
#pragma unroll
        for (int jj = 0; jj < 8; jj++) acc[i][jj] = 0.f;

    for (int k0 = 0; k0 < 1024; k0 += 16) {
#pragma unroll
        for (int l = 0; l < 2; l++) {
            const int c = tid + l * 256;
            const int row = c >> 2;
            const int f4 = c & 3;
            float4 av = *reinterpret_cast<const float4*>(
                x + (size_t)(m0 + row) * 1024 + k0 + f4 * 4);
            float4 bv = *reinterpret_cast<const float4*>(
                Wih + (size_t)(n0 + row) * 1024 + k0 + f4 * 4);
            a_lds[f4 * 4 + 0][row] = av.x; a_lds[f4 * 4 + 1][row] = av.y;
            a_lds[f4 * 4 + 2][row] = av.z; a_lds[f4 * 4 + 3][row] = av.w;
            b_lds[f4 * 4 + 0][row] = bv.x; b_lds[f4 * 4 + 1][row] = bv.y;
            b_lds[f4 * 4 + 2][row] = bv.z; b_lds[f4 * 4 + 3][row] = bv.w;
        }
        __syncthreads();
#pragma unroll
        for (int kk = 0; kk < 16; kk++) {
            float a[8], b[8];
            *reinterpret_cast<float4*>(&a[0]) =
                *reinterpret_cast<float4*>(&a_lds[kk][ty * 8]);
            *reinterpret_cast<float4*>(&a[4]) =
                *reinterpret_cast<float4*>(&a_lds[kk][ty * 8 + 4]);
            *reinterpret_cast<float4*>(&b[0]) =
                *reinterpret_cast<float4*>(&b_lds[kk][tx * 8]);
            *reinterpret_cast<float4*>(&b[4]) =
                *reinterpret_cast<float4*>(&b_lds[kk][tx * 8 + 4]);
#pragma unroll
            for (int i = 0; i < 8; i++)
#pragma unroll
                for (int jj = 0; jj < 8; jj++)
                    acc[i][jj] = fmaf(a[i], b[jj], acc[i][jj]);
        }
        __syncthreads();
    }

    float bias[8];
    *reinterpret_cast<float4*>(&bias[0]) =
        *reinterpret_cast<const float4*>(bih + n0 + tx * 8);
    *reinterpret_cast<float4*>(&bias[4]) =
        *reinterpret_cast<const float4*>(bih + n0 + tx * 8 + 4);
    // m = b*T + t; 128-row m-tiles never straddle a batch (T=2048 % 128 == 0)
#pragma unroll
    for (int i = 0; i < 8; i++) {
        const int m = m0 + ty * 8 + i;
        const int b = m >> 11;        // m / 2048
        const int t = m & 2047;
#pragma unroll
        for (int jj = 0; jj < 8; jj++) {
            const int n = n0 + tx * 8 + jj;   // = g*1024 + jcol, folded
            xproj[((size_t)t * 3072 + n) * 8 + b] = acc[i][jj] + bias[jj];
        }
    }
}

// ---------------- Phase 2: sequential GRU scan ----------------
// 256 blocks x 256 threads, co-resident (1 block/CU). Wave w of block bid
// owns j = bid*4 + w (all 3 gates, all 8 batches). W_hh fragment in VGPRs
// with a stride-64 k-interleave (k = lane + 64*i) so the LDS h reads are
// bank-conflict-free (bank = lane mod 32 -> 2-way = free).
// Per step: poll flags -> stage h (32 KB) into LDS via coalesced sc1 u64
// loads -> LDS reads + 384 FMA/lane -> wave butterfly reduce -> gate math
// on lanes 0..7 -> sc1 h store + plain out store -> vmcnt drain ->
// __syncthreads -> sc1 flag release.
__global__ __launch_bounds__(256, 1) void gru_scan(
        const float* __restrict__ Whh, const float* __restrict__ bhh,
        const float* __restrict__ xproj, float* __restrict__ out,
        float* __restrict__ hbuf, unsigned int* __restrict__ flags) {
    __shared__ float hshare[BATCH * HID];   // 32 KB, [b][k]
    const int tid = threadIdx.x;
    const int bid = blockIdx.x;
    const int wave = tid >> 6;
    const int lane = tid & 63;
    const int j = bid * 4 + wave;        // [0, 1024)

    // loop-invariant W_hh fragment: rows g*1024+j, k = lane + 64*i
    float wf[3][16];
#pragma unroll
    for (int g = 0; g < 3; g++)
#pragma unroll
        for (int i = 0; i < 16; i++)
            wf[g][i] = Whh[(size_t)(g * 1024 + j) * 1024 + lane + 64 * i];

    const float bh0 = bhh[j], bh1 = bhh[1024 + j], bh2 = bhh[2048 + j];

    // ---- t = 0: h_prev = 0 -> g_h = b_hh ----
    if (lane < 8) {
        const size_t xb = (size_t)0 * 3072 + j;   // t = 0
        const float gxr = xproj[(xb) * 8 + lane];
        const float gxz = xproj[(xb + 1024) * 8 + lane];
        const float gxn = xproj[(xb + 2048) * 8 + lane];
        const float r = sigmoidf_(gxr + bh0);
        const float z = sigmoidf_(gxz + bh1);
        const float n = tanhf(gxn + r * bh2);
        const float hnew = (1.f - z) * n;
        st_f32_agent(hbuf + lane * HID + j, hnew);
        out[((size_t)lane * T_STEPS) * HID + j] = hnew;
    }
    drain_vmem();
    __syncthreads();
    if (tid == 0) st_u32_agent(&flags[bid], 1u);

    for (int t = 1; t < T_STEPS; t++) {
        // prefetch gx for this step (plain cached loads; 3 contiguous 32B
        // chunks per wave thanks to the [t][g][j][b] repack)
        float gxr = 0.f, gxz = 0.f, gxn = 0.f;
        if (lane < 8) {
            const size_t xb = (size_t)t * 3072 + j;
            gxr = xproj[(xb) * 8 + lane];
            gxz = xproj[(xb + 1024) * 8 + lane];
            gxn = xproj[(xb + 2048) * 8 + lane];
        }

        // wait until every block finished step t-1 (one flag per thread)
        const unsigned int* fl = &flags[(size_t)(t - 1) * 256 + tid];
        while (ld_u32_agent(fl) != 1u)
            __builtin_amdgcn_s_sleep(1);
        __syncthreads();   // all 256 flags confirmed block-wide

        // ---- stage h(t-1) (32 KB) into LDS: coalesced sc1 u64 loads ----
        const float* hsrc = hbuf + ((t - 1) & 1) * (BATCH * HID);
        unsigned long long hl[16];
#pragma unroll
        for (int i = 0; i < 16; i++)
            hl[i] = ld_u64_agent(hsrc + 2 * (tid + 256 * i));
#pragma unroll
        for (int i = 0; i < 16; i++)
            *reinterpret_cast<unsigned long long*>(
                &hshare[2 * (tid + 256 * i)]) = hl[i];
        __syncthreads();

        const float hprev = (lane < 8) ? hshare[lane * HID + j] : 0.f;

        float acc[3][8];
#pragma unroll
        for (int g = 0; g < 3; g++)
#pragma unroll
            for (int b = 0; b < 8; b++) acc[g][b] = 0.f;
#pragma unroll
        for (int b = 0; b < 8; b++) {
            float hv[16];
#pragma unroll
            for (int i = 0; i < 16; i++)
                hv[i] = hshare[b * HID + lane + 64 * i];
#pragma unroll
            for (int g = 0; g < 3; g++)
#pragma unroll
                for (int i = 0; i < 16; i++)
                    acc[g][b] = fmaf(wf[g][i], hv[i], acc[g][b]);
        }

        // full-wave butterfly all-reduce over the 64-way K split
#pragma unroll
        for (int m = 32; m >= 1; m >>= 1)
#pragma unroll
            for (int g = 0; g < 3; g++)
#pragma unroll
                for (int b = 0; b < 8; b++)
                    acc[g][b] += __shfl_xor(acc[g][b], m);

        float* hdst = hbuf + (t & 1) * (BATCH * HID);
        if (lane < 8) {
            float aa0 = 0.f, aa1 = 0.f, aa2 = 0.f;
#pragma unroll
            for (int b = 0; b < 8; b++)
                if (lane == b) { aa0 = acc[0][b]; aa1 = acc[1][b]; aa2 = acc[2][b]; }
            const float r = sigmoidf_(gxr + aa0 + bh0);
            const float z = sigmoidf_(gxz + aa1 + bh1);
            const float n = tanhf(gxn + r * (aa2 + bh2));
            const float hnew = (1.f - z) * n + z * hprev;
            st_f32_agent(hdst + lane * HID + j, hnew);
            out[((size_t)lane * T_STEPS + t) * HID + j] = hnew;
        }
        drain_vmem();      // sc1 h stores at the IF before the flag release
        __syncthreads();
        if (tid == 0) st_u32_agent(&flags[(size_t)t * 256 + bid], 1u);
    }
}

extern "C" void kernel_launch(void* const* d_in, const int* in_sizes, int n_in,
                              void* d_out, int out_size, void* d_ws,
                              size_t ws_size, hipStream_t stream) {
    const float* x    = (const float*)d_in[0];
    const float* Wih  = (const float*)d_in[1];
    const float* bih  = (const float*)d_in[2];
    const float* Whh  = (const float*)d_in[3];
    const float* bhh  = (const float*)d_in[4];
    float* outp = (float*)d_out;

    float* xproj = (float*)d_ws;
    float* hbuf  = xproj + XPROJ_F;
    unsigned int* flags = (unsigned int*)((char*)d_ws + FLAGS_BYTE_OFF);

    dim3 g1(128, 24);   // M/128, N/128
    gemm_xproj<<<g1, 256, 0, stream>>>(x, Wih, bih, xproj);
    gru_scan<<<256, 256, 0, stream>>>(Whh, bhh, xproj, outp, hbuf, flags);
}

// Round 4
// 18503.018 us; speedup vs baseline: 5.8970x; 1.0100x over previous
//
#include <hip/hip_runtime.h>

#define T_STEPS 2048
#define BATCH 8
#define HID 1024

// ws layout:
//   floats [0, 50331648)      x_proj repacked [t][gate][j][b] (t*3072+g*1024+j)*8+b
//   byte 201326592 (=192MiB): h double buffer, 2 x 8192 u64 {tag(hi32), f32 h(lo32)}
//                             element index e = b*1024 + k; production step s -> buffer s&1,
//                             tag = s+1. 128 KiB total. (ws poison 0xAAAAAAAA never matches a tag.)
#define XPROJ_F 50331648ull
#define HBUF64_BYTE_OFF 201326592ull

__device__ __forceinline__ float sigmoidf_(float x) {
    return 1.0f / (1.0f + __expf(-x));
}

// Relaxed AGENT-scope atomics lower to global_load/store ... sc1 — they read/
// write the Infinity Cache (the inter-XCD coherence point) with NO L2
// writeback/invalidate. An aligned 8B store is single-copy atomic, so the
// {tag, value} packet is self-validating: no flags, no fences, no drains.
__device__ __forceinline__ unsigned long long ld_u64_agent(const unsigned long long* p) {
    return __hip_atomic_load(p, __ATOMIC_RELAXED, __HIP_MEMORY_SCOPE_AGENT);
}
__device__ __forceinline__ void st_u64_agent(unsigned long long* p, unsigned long long v) {
    __hip_atomic_store(p, v, __ATOMIC_RELAXED, __HIP_MEMORY_SCOPE_AGENT);
}

// ---------------- Phase 1: x_proj = x @ W_ih^T + b_ih ----------------
// 128x128 tile, BK=16, 256 threads, 8x8 micro-tile. Epilogue scatters into
// the [t][gate][j][b] layout the scan wants. (Unchanged from R3.)
__global__ __launch_bounds__(256) void gemm_xproj(
        const float* __restrict__ x, const float* __restrict__ Wih,
        const float* __restrict__ bih, float* __restrict__ xproj) {
    __shared__ float a_lds[16][128];  // [k][m]
    __shared__ float b_lds[16][128];  // [k][n]
    const int tid = threadIdx.x;
    const int m0 = blockIdx.x * 128;
    const int n0 = blockIdx.y * 128;
    const int tx = tid & 15, ty = tid >> 4;

    float acc[8][8];
#pragma unroll
    for (int i = 0; i < 8; i++)
#pragma unroll
        for (int jj = 0; jj < 8; jj++) acc[i][jj] = 0.f;

    for (int k0 = 0; k0 < 1024; k0 += 16) {
#pragma unroll
        for (int l = 0; l < 2; l++) {
            const int c = tid + l * 256;
            const int row = c >> 2;
            const int f4 = c & 3;
            float4 av = *reinterpret_cast<const float4*>(
                x + (size_t)(m0 + row) * 1024 + k0 + f4 * 4);
            float4 bv = *reinterpret_cast<const float4*>(
                Wih + (size_t)(n0 + row) * 1024 + k0 + f4 * 4);
            a_lds[f4 * 4 + 0][row] = av.x; a_lds[f4 * 4 + 1][row] = av.y;
            a_lds[f4 * 4 + 2][row] = av.z; a_lds[f4 * 4 + 3][row] = av.w;
            b_lds[f4 * 4 + 0][row] = bv.x; b_lds[f4 * 4 + 1][row] = bv.y;
            b_lds[f4 * 4 + 2][row] = bv.z; b_lds[f4 * 4 + 3][row] = bv.w;
        }
        __syncthreads();
#pragma unroll
        for (int kk = 0; kk < 16; kk++) {
            float a[8], b[8];
            *reinterpret_cast<float4*>(&a[0]) =
                *reinterpret_cast<float4*>(&a_lds[kk][ty * 8]);
            *reinterpret_cast<float4*>(&a[4]) =
                *reinterpret_cast<float4*>(&a_lds[kk][ty * 8 + 4]);
            *reinterpret_cast<float4*>(&b[0]) =
                *reinterpret_cast<float4*>(&b_lds[kk][tx * 8]);
            *reinterpret_cast<float4*>(&b[4]) =
                *reinterpret_cast<float4*>(&b_lds[kk][tx * 8 + 4]);
#pragma unroll
            for (int i = 0; i < 8; i++)
#pragma unroll
                for (int jj = 0; jj < 8; jj++)
                    acc[i][jj] = fmaf(a[i], b[jj], acc[i][jj]);
        }
        __syncthreads();
    }

    float bias[8];
    *reinterpret_cast<float4*>(&bias[0]) =
        *reinterpret_cast<const float4*>(bih + n0 + tx * 8);
    *reinterpret_cast<float4*>(&bias[4]) =
        *reinterpret_cast<const float4*>(bih + n0 + tx * 8 + 4);
    // m = b*T + t; 128-row m-tiles never straddle a batch (T=2048 % 128 == 0)
#pragma unroll
    for (int i = 0; i < 8; i++) {
        const int m = m0 + ty * 8 + i;
        const int b = m >> 11;        // m / 2048
        const int t = m & 2047;
#pragma unroll
        for (int jj = 0; jj < 8; jj++) {
            const int n = n0 + tx * 8 + jj;   // = g*1024 + jcol, folded
            xproj[((size_t)t * 3072 + n) * 8 + b] = acc[i][jj] + bias[jj];
        }
    }
}

// ---------------- Phase 2: sequential GRU scan ----------------
// 256 blocks x 256 threads, co-resident (1 block/CU). Wave w of block bid
// owns j = bid*4 + w. W_hh fragment in VGPRs (stride-64 k-interleave so LDS
// h reads are conflict-free). Per step: prefetch gx -> issue 32 pipelined
// u64 {tag,h} loads, retry stale ones -> LDS stage -> sync -> 384 FMA/lane
// -> butterfly all-reduce -> gates on lanes 0..7 -> single u64 sc1 h store
// (data IS the flag) + plain out store -> sync.
__global__ __launch_bounds__(256, 1) void gru_scan(
        const float* __restrict__ Whh, const float* __restrict__ bhh,
        const float* __restrict__ xproj, float* __restrict__ out,
        unsigned long long* __restrict__ hbuf64) {
    __shared__ float hshare[BATCH * HID];   // 32 KB, [b][k]
    const int tid = threadIdx.x;
    const int bid = blockIdx.x;
    const int wave = tid >> 6;
    const int lane = tid & 63;
    const int j = bid * 4 + wave;        // [0, 1024)

    // loop-invariant W_hh fragment: rows g*1024+j, k = lane + 64*i
    float wf[3][16];
#pragma unroll
    for (int g = 0; g < 3; g++)
#pragma unroll
        for (int i = 0; i < 16; i++)
            wf[g][i] = Whh[(size_t)(g * 1024 + j) * 1024 + lane + 64 * i];

    const float bh0 = bhh[j], bh1 = bhh[1024 + j], bh2 = bhh[2048 + j];

    // ---- t = 0: h_prev = 0 -> g_h = b_hh ----
    if (lane < 8) {
        const size_t xb = (size_t)0 * 3072 + j;
        const float gxr = xproj[(xb) * 8 + lane];
        const float gxz = xproj[(xb + 1024) * 8 + lane];
        const float gxn = xproj[(xb + 2048) * 8 + lane];
        const float r = sigmoidf_(gxr + bh0);
        const float z = sigmoidf_(gxz + bh1);
        const float n = tanhf(gxn + r * bh2);
        const float hnew = (1.f - z) * n;
        // buffer parity 0, tag 1
        st_u64_agent(hbuf64 + (size_t)lane * HID + j,
                     ((unsigned long long)1u << 32) | __float_as_uint(hnew));
        out[((size_t)lane * T_STEPS) * HID + j] = hnew;
    }

    for (int t = 1; t < T_STEPS; t++) {
        // prefetch gx (plain cached loads, overlap the staging latency)
        float gxr = 0.f, gxz = 0.f, gxn = 0.f;
        if (lane < 8) {
            const size_t xb = (size_t)t * 3072 + j;
            gxr = xproj[(xb) * 8 + lane];
            gxz = xproj[(xb + 1024) * 8 + lane];
            gxn = xproj[(xb + 2048) * 8 + lane];
        }

        // ---- stage h(t-1): 32 pipelined u64 loads, tag-validated ----
        const unsigned long long* src = hbuf64 + (size_t)((t - 1) & 1) * 8192;
        const unsigned expect = (unsigned)t;     // tag of h produced at step t-1
        unsigned long long v[32];
#pragma unroll
        for (int i = 0; i < 32; i++)
            v[i] = ld_u64_agent(src + tid + 256 * i);
        for (;;) {
            unsigned bad = 0;
#pragma unroll
            for (int i = 0; i < 32; i++)
                bad |= (unsigned)(v[i] >> 32) ^ expect;
            if (bad == 0) break;
            __builtin_amdgcn_s_sleep(1);
#pragma unroll
            for (int i = 0; i < 32; i++)
                if ((unsigned)(v[i] >> 32) != expect)
                    v[i] = ld_u64_agent(src + tid + 256 * i);
        }
#pragma unroll
        for (int i = 0; i < 32; i++)
            hshare[tid + 256 * i] = __uint_as_float((unsigned)v[i]);
        __syncthreads();   // whole block validated + staged all of h(t-1)

        const float hprev = (lane < 8) ? hshare[lane * HID + j] : 0.f;

        float acc[3][8];
#pragma unroll
        for (int g = 0; g < 3; g++)
#pragma unroll
            for (int b = 0; b < 8; b++) acc[g][b] = 0.f;
#pragma unroll
        for (int b = 0; b < 8; b++) {
            float hv[16];
#pragma unroll
            for (int i = 0; i < 16; i++)
                hv[i] = hshare[b * HID + lane + 64 * i];
#pragma unroll
            for (int g = 0; g < 3; g++)
#pragma unroll
                for (int i = 0; i < 16; i++)
                    acc[g][b] = fmaf(wf[g][i], hv[i], acc[g][b]);
        }

        // full-wave butterfly all-reduce over the 64-way K split
#pragma unroll
        for (int m = 32; m >= 1; m >>= 1)
#pragma unroll
            for (int g = 0; g < 3; g++)
#pragma unroll
                for (int b = 0; b < 8; b++)
                    acc[g][b] += __shfl_xor(acc[g][b], m);

        if (lane < 8) {
            float aa0 = 0.f, aa1 = 0.f, aa2 = 0.f;
#pragma unroll
            for (int b = 0; b < 8; b++)
                if (lane == b) { aa0 = acc[0][b]; aa1 = acc[1][b]; aa2 = acc[2][b]; }
            const float r = sigmoidf_(gxr + aa0 + bh0);
            const float z = sigmoidf_(gxz + aa1 + bh1);
            const float n = tanhf(gxn + r * (aa2 + bh2));
            const float hnew = (1.f - z) * n + z * hprev;
            // single self-validating packet: {tag = t+1, h}
            st_u64_agent(hbuf64 + (size_t)(t & 1) * 8192 + lane * HID + j,
                         ((unsigned long long)(unsigned)(t + 1) << 32) |
                             __float_as_uint(hnew));
            out[((size_t)lane * T_STEPS + t) * HID + j] = hnew;
        }
        __syncthreads();   // hshare reads done before next staging overwrites
    }
}

extern "C" void kernel_launch(void* const* d_in, const int* in_sizes, int n_in,
                              void* d_out, int out_size, void* d_ws,
                              size_t ws_size, hipStream_t stream) {
    const float* x    = (const float*)d_in[0];
    const float* Wih  = (const float*)d_in[1];
    const float* bih  = (const float*)d_in[2];
    const float* Whh  = (const float*)d_in[3];
    const float* bhh  = (const float*)d_in[4];
    float* outp = (float*)d_out;

    float* xproj = (float*)d_ws;
    unsigned long long* hbuf64 =
        (unsigned long long*)((char*)d_ws + HBUF64_BYTE_OFF);

    dim3 g1(128, 24);   // M/128, N/128
    gemm_xproj<<<g1, 256, 0, stream>>>(x, Wih, bih, xproj);
    gru_scan<<<256, 256, 0, stream>>>(Whh, bhh, xproj, outp, hbuf64);
}